// Round 6
// baseline (161.433 us; speedup 1.0000x reference)
//
#include <hip/hip_runtime.h>

// ---------------------------------------------------------------------------
// DCT-conv:  out = IDCT_H( circconv_W( DCT_H(x), DCT_H(pad(w)) ) summed over ci ) + bias
// B=8, c_in=64, c_out=128, H=W=128, kh=kw=5.
//
// Pipeline (fp16 storage, fp32 MFMA accumulate), 3 dispatches:
//   k_prep : blocks 0..1023  = DCT_H (xd[k][b][ci][w] = D @ x, D computed inline)
//            blocks 1024..1279 = WD gen + M matrix
//   k_conv : y2[b][k][co][w] = sum_{j,ci} WD * xd shifted  (1024 wgs, b-major)
//   k_idct : out[b][co][h][w] = M @ y2 + bias  (2048 wgs, w-split for occupancy)
// ---------------------------------------------------------------------------

using half8v = __attribute__((ext_vector_type(8))) _Float16;
using half4v = __attribute__((ext_vector_type(4))) _Float16;
using f32x4  = __attribute__((ext_vector_type(4))) float;

#define PI_F 3.14159265358979323846f

// XOR-swizzled LDS offset for [n][K] layouts (16B chunks of 8 fp16).
__device__ __forceinline__ int sw_off(int n, int k, int K, int mask) {
    int c = k >> 3;
    return n * K + (((c ^ (n & mask)) << 3) | (k & 7));
}

// ---------------------------------------------------------------------------
// k_prep: blocks 0..1023: dctH for (b = bid>>7, ci = (bid>>1)&63, wh = bid&1).
//         blocks 1024..1279: WD for (co = bid'>>1, k0 = (bid'&1)*64); bid'<128
//         also emits M.
__global__ __launch_bounds__(256) void k_prep(const float* __restrict__ x,
                                              const float* __restrict__ w,
                                              _Float16* __restrict__ xd,
                                              _Float16* __restrict__ WD,
                                              _Float16* __restrict__ M) {
    __shared__ union {
        _Float16 lB[64 * 128];          // 16 KB  (dctH path: [w][h] swizzled)
        struct { float lw[1600]; float lcos[320]; } wd;  // 7.7 KB (WD path)
    } sm;
    int bid = blockIdx.x;
    int tid = threadIdx.x;

    if (bid >= 1024) {
        // ---------------- WD path ----------------
        int bp = bid - 1024;
        int co = bp >> 1, k0 = (bp & 1) << 6;
        if (bp < 128 && tid < 128) {
            int k = bp, h = tid;
            float ang = PI_F * (float)((2 * h + 1) * k) * (1.0f / 256.0f);
            float wk = (k == 0) ? 0.5f : 1.0f;
            M[h * 128 + k] = (_Float16)(cosf(ang) * wk * (1.0f / 256.0f));
        }
        for (int e = tid; e < 1600; e += 256) sm.wd.lw[e] = w[co * 1600 + e];
        for (int e = tid; e < 320; e += 256) {
            int kl = e / 5, i = e - kl * 5;
            sm.wd.lcos[e] = 2.0f * cosf(PI_F * (float)((2 * i + 1) * (k0 + kl)) * (1.0f / 256.0f));
        }
        __syncthreads();
        for (int e = tid; e < 20480; e += 256) {
            int kk = e & 31, rest = e >> 5;
            int s = rest % 10, kl = rest / 10;
            int j = s >> 1, ci = ((s & 1) << 5) + kk;
            const float* wp = &sm.wd.lw[ci * 25 + j];
            const float* cp = &sm.wd.lcos[kl * 5];
            float acc = 0.f;
#pragma unroll
            for (int i = 0; i < 5; ++i) acc += cp[i] * wp[i * 5];
            WD[(((long)(k0 + kl) * 10 + s) * 128 + co) * 32 + kk] = (_Float16)acc;
        }
        return;
    }

    // ---------------- dctH path ----------------
    // xd[k][b][ci][wh*64 + w] = sum_h D[k][h] * x[b][ci][h][wh*64 + w]
    int b = bid >> 7, ci = (bid >> 1) & 63, wh = bid & 1;
    const float* xs = x + (long)(b * 64 + ci) * 16384 + wh * 64;

    {   // stage x slice [128 h][64 w] -> lB [64 w][128 h] swizzled (fp16)
        int kb = tid >> 3, wb = tid & 7;
        int h0 = kb * 4, w0 = wb * 8;
        f32x4 f[4][2];
#pragma unroll
        for (int dh = 0; dh < 4; ++dh) {
            f[dh][0] = *(const f32x4*)(&xs[(h0 + dh) * 128 + w0]);
            f[dh][1] = *(const f32x4*)(&xs[(h0 + dh) * 128 + w0 + 4]);
        }
#pragma unroll
        for (int dw = 0; dw < 8; ++dw) {
            int n = w0 + dw;
            half4v p = {(_Float16)f[0][dw >> 2][dw & 3], (_Float16)f[1][dw >> 2][dw & 3],
                        (_Float16)f[2][dw >> 2][dw & 3], (_Float16)f[3][dw >> 2][dw & 3]};
            *(half4v*)(&sm.lB[sw_off(n, h0, 128, 15)]) = p;
        }
    }
    __syncthreads();

    int lane = tid & 63, ln = lane & 15, q = lane >> 4;
    int wave = tid >> 6, wm = wave >> 1, wn = wave & 1;
    f32x4 acc[4][2] = {};

#pragma unroll
    for (int s = 0; s < 4; ++s) {
        half8v af[4], bf[2];
#pragma unroll
        for (int mt = 0; mt < 4; ++mt) {
            int m = wm * 64 + mt * 16 + ln;          // DCT index k
            int h0 = s * 32 + q * 8;
            float mf = (float)m * (PI_F / 256.0f);
#pragma unroll
            for (int j = 0; j < 8; ++j)
                af[mt][j] = (_Float16)(2.0f * cosf((float)(2 * (h0 + j) + 1) * mf));
        }
#pragma unroll
        for (int nt = 0; nt < 2; ++nt) {
            int n = wn * 32 + nt * 16 + ln;
            bf[nt] = *(const half8v*)(&sm.lB[n * 128 + (((s * 4 + q) ^ (n & 15)) << 3)]);
        }
#pragma unroll
        for (int mt = 0; mt < 4; ++mt)
#pragma unroll
            for (int nt = 0; nt < 2; ++nt)
                acc[mt][nt] = __builtin_amdgcn_mfma_f32_16x16x32_f16(bf[nt], af[mt], acc[mt][nt], 0, 0, 0);
    }

#pragma unroll
    for (int mt = 0; mt < 4; ++mt)
#pragma unroll
        for (int nt = 0; nt < 2; ++nt) {
            int kk = wm * 64 + mt * 16 + ln;
            int w0 = wh * 64 + wn * 32 + nt * 16 + q * 4;
            half4v p = {(_Float16)acc[mt][nt][0], (_Float16)acc[mt][nt][1],
                        (_Float16)acc[mt][nt][2], (_Float16)acc[mt][nt][3]};
            *(half4v*)(&xd[((long)(kk * 8 + b) * 64 + ci) * 128 + w0]) = p;
        }
}

// ---------------------------------------------------------------------------
// Step B: per (k,b):  y2[b][k][co][w] = sum_{s,kk} WD[k][s][co][kk] * xd[k][b][ci][(w-j)&127]
// b-major grid keeps the 80 KB WD k-tile L2-resident across the 8 batches.
// WD A-fragments read directly from global; barrier-free 10-stage loop.
__global__ __launch_bounds__(256) void k_conv(const _Float16* __restrict__ xd,
                                              const _Float16* __restrict__ WD,
                                              _Float16* __restrict__ y2) {
    __shared__ _Float16 lX[128 * 64];        // [w][ci] swizzled, mask=7   (16 KB)
    int bid = blockIdx.x;
    int k = bid & 127, b = bid >> 7;
    int tid = threadIdx.x;

    {   // stage xd^T (64 ci-rows of 128 w) -> lX [w][ci]
        const _Float16* src = xd + (long)(k * 8 + b) * 8192;
        int kb = tid >> 4, wb = tid & 15;
        int k0 = kb * 4, w0 = wb * 8;
        half8v r0 = *(const half8v*)(&src[(k0 + 0) * 128 + w0]);
        half8v r1 = *(const half8v*)(&src[(k0 + 1) * 128 + w0]);
        half8v r2 = *(const half8v*)(&src[(k0 + 2) * 128 + w0]);
        half8v r3 = *(const half8v*)(&src[(k0 + 3) * 128 + w0]);
#pragma unroll
        for (int dw = 0; dw < 8; ++dw) {
            int n = w0 + dw;
            half4v p = {r0[dw], r1[dw], r2[dw], r3[dw]};
            *(half4v*)(&lX[sw_off(n, k0, 64, 7)]) = p;
        }
    }
    __syncthreads();

    int lane = tid & 63, ln = lane & 15, q = lane >> 4;
    int wave = tid >> 6, wm = wave >> 1, wn = wave & 1;
    f32x4 acc[4][4] = {};

    const _Float16* wkb = WD + (long)k * 40960;   // k * 10 * 4096

    for (int s = 0; s < 10; ++s) {
        int j = s >> 1;
        int cb = (s & 1) << 2;   // ci-chunk base within K=64
        const _Float16* wt = wkb + s * 4096;
        half8v af[4], bf[4];
#pragma unroll
        for (int mt = 0; mt < 4; ++mt) {
            int m = wm * 64 + mt * 16 + ln;
            af[mt] = *(const half8v*)(&wt[m * 32 + q * 8]);   // global, L2-hot
        }
#pragma unroll
        for (int nt = 0; nt < 4; ++nt) {
            int wcol = wn * 64 + nt * 16 + ln;
            int n = (wcol - j) & 127;
            bf[nt] = *(const half8v*)(&lX[n * 64 + (((cb + q) ^ (n & 7)) << 3)]);
        }
#pragma unroll
        for (int mt = 0; mt < 4; ++mt)
#pragma unroll
            for (int nt = 0; nt < 4; ++nt)
                acc[mt][nt] = __builtin_amdgcn_mfma_f32_16x16x32_f16(bf[nt], af[mt], acc[mt][nt], 0, 0, 0);
    }

    _Float16* yb = y2 + (long)(b * 128 + k) * 16384;
#pragma unroll
    for (int mt = 0; mt < 4; ++mt)
#pragma unroll
        for (int nt = 0; nt < 4; ++nt) {
            int co = wm * 64 + mt * 16 + ln;
            int w0 = wn * 64 + nt * 16 + q * 4;
            half4v p = {(_Float16)acc[mt][nt][0], (_Float16)acc[mt][nt][1],
                        (_Float16)acc[mt][nt][2], (_Float16)acc[mt][nt][3]};
            *(half4v*)(&yb[co * 128 + w0]) = p;
        }
}

// ---------------------------------------------------------------------------
// Step C: out[b][co][h][w] = sum_k M[h][k] * y2[b][k][co][w] + bias[co]
// 2048 blocks: (b = bid>>8, co = (bid>>1)&127, wh = bid&1); 16 KB LDS.
__global__ __launch_bounds__(256) void k_idct(const _Float16* __restrict__ y2,
                                              const _Float16* __restrict__ Mg,
                                              const float* __restrict__ bias,
                                              float* __restrict__ out) {
    __shared__ _Float16 lB[64 * 128];     // [w][k] swizzled, 16 KB
    int bid = blockIdx.x;
    int b = bid >> 8, co = (bid >> 1) & 127, wh = bid & 1;
    int tid = threadIdx.x;

    {   // stage y2 slice [128 k][64 w] (row stride 16384) -> lB [w][k]
        const _Float16* src = y2 + (long)b * 2097152 + co * 128 + wh * 64;
        int kb = tid >> 3, wb = tid & 7;
        int k0 = kb * 4, w0 = wb * 8;
        half8v r0 = *(const half8v*)(&src[(long)(k0 + 0) * 16384 + w0]);
        half8v r1 = *(const half8v*)(&src[(long)(k0 + 1) * 16384 + w0]);
        half8v r2 = *(const half8v*)(&src[(long)(k0 + 2) * 16384 + w0]);
        half8v r3 = *(const half8v*)(&src[(long)(k0 + 3) * 16384 + w0]);
#pragma unroll
        for (int dw = 0; dw < 8; ++dw) {
            int n = w0 + dw;
            half4v p = {r0[dw], r1[dw], r2[dw], r3[dw]};
            *(half4v*)(&lB[sw_off(n, k0, 128, 15)]) = p;
        }
    }
    __syncthreads();

    int lane = tid & 63, ln = lane & 15, q = lane >> 4;
    int wave = tid >> 6, wm = wave >> 1, wn = wave & 1;
    f32x4 acc[4][2] = {};

#pragma unroll
    for (int s = 0; s < 4; ++s) {
        half8v af[4], bf[2];
#pragma unroll
        for (int mt = 0; mt < 4; ++mt) {
            int m = wm * 64 + mt * 16 + ln;          // h row of M
            af[mt] = *(const half8v*)(&Mg[m * 128 + (s * 4 + q) * 8]);
        }
#pragma unroll
        for (int nt = 0; nt < 2; ++nt) {
            int n = wn * 32 + nt * 16 + ln;
            bf[nt] = *(const half8v*)(&lB[n * 128 + (((s * 4 + q) ^ (n & 15)) << 3)]);
        }
#pragma unroll
        for (int mt = 0; mt < 4; ++mt)
#pragma unroll
            for (int nt = 0; nt < 2; ++nt)
                acc[mt][nt] = __builtin_amdgcn_mfma_f32_16x16x32_f16(bf[nt], af[mt], acc[mt][nt], 0, 0, 0);
    }

    float bv = bias[co];
    float* ob = out + ((long)(b * 128 + co)) * 16384;
#pragma unroll
    for (int mt = 0; mt < 4; ++mt)
#pragma unroll
        for (int nt = 0; nt < 2; ++nt) {
            int h = wm * 64 + mt * 16 + ln;
            int w0 = wh * 64 + wn * 32 + nt * 16 + q * 4;
            f32x4 p = {acc[mt][nt][0] + bv, acc[mt][nt][1] + bv,
                       acc[mt][nt][2] + bv, acc[mt][nt][3] + bv};
            *(f32x4*)(&ob[h * 128 + w0]) = p;
        }
}

// ---------------------------------------------------------------------------
extern "C" void kernel_launch(void* const* d_in, const int* in_sizes, int n_in,
                              void* d_out, int out_size, void* d_ws, size_t ws_size,
                              hipStream_t stream) {
    const float* x    = (const float*)d_in[0];  // [8][64][128][128]
    const float* w    = (const float*)d_in[1];  // [128][64][5][5]
    const float* bias = (const float*)d_in[2];  // [128]
    float* out = (float*)d_out;                 // [8][128][128][128]

    char* ws = (char*)d_ws;
    _Float16* M  = (_Float16*)(ws);                                  //  32 KB
    _Float16* WD = (_Float16*)(ws + 32768);                          //  10.0 MB
    _Float16* xd = (_Float16*)(ws + 32768 + 10485760);               //  16 MB
    _Float16* y2 = (_Float16*)(ws + 32768 + 10485760 + 16777216);    //  32 MB

    k_prep<<<dim3(1280), dim3(256), 0, stream>>>(x, w, xd, WD, M);
    k_conv<<<dim3(1024), dim3(256), 0, stream>>>(xd, WD, y2);
    k_idct<<<dim3(2048), dim3(256), 0, stream>>>(y2, M, bias, out);
}